// Round 1
// baseline (4329.523 us; speedup 1.0000x reference)
//
#include <hip/hip_runtime.h>

#define DEV __device__ __forceinline__

DEV float bf2f(unsigned short u) {
  union { unsigned int i; float f; } v; v.i = ((unsigned int)u) << 16; return v.f;
}
DEV unsigned short f2bf(float f) {
  union { float f; unsigned int i; } v; v.f = f;
  unsigned int x = v.i;
  return (unsigned short)((x + 0x7fffu + ((x >> 16) & 1u)) >> 16);
}
DEV float softplusf(float v) { return v > 20.f ? v : log1pf(__expf(v)); }
DEV float siluf(float v) { return v / (1.f + __expf(-v)); }
DEV float comp4(float4 v, int k) {
  return k == 0 ? v.x : (k == 1 ? v.y : (k == 2 ? v.z : v.w));
}
// swizzled index into the [64][260] xcz tile (bank-spread for both d-major and
// k-major float4 access). XOR of bits 2..4 keeps 4-element blocks contiguous.
DEV int xidx(int t, int d) { return t * 260 + (d ^ (((t >> 1) & 7) << 2)); }

// ---------------------------------------------------------------------------
// Fused mamba front: xz GEMM -> causal conv+silu -> x_proj -> softplus(dt)
// -> selective scan -> gate with silu(z) -> w_out GEMM.  One block = one
// sequence (W=64).  Output written directly to its slot in d_out.
// ---------------------------------------------------------------------------
__global__ __launch_bounds__(256) void mamba_front(
    const float* __restrict__ x, int SEQ, int slot_base,
    const float* __restrict__ w_in, const float* __restrict__ conv_w,
    const float* __restrict__ conv_b, const float* __restrict__ w_xp,
    const float* __restrict__ dt_w, const float* __restrict__ dt_b,
    const float* __restrict__ Alog, const float* __restrict__ Dp,
    const float* __restrict__ w_out, float* __restrict__ out)
{
  __shared__ __align__(16) char pool[151552];
  float* xcz          = (float*)pool;                          // [64][260] f32 (xc, then gated y)
  unsigned short* zls = (unsigned short*)(pool + 66560);       // [64][256] bf16 (z)
  unsigned short* xlsT= (unsigned short*)(pool + 99328);       // [128][68] bf16 (x transposed)
  unsigned short* wt1 = (unsigned short*)(pool + 116736);      // [128][136] bf16 (w_in tile)
  float* wxp          = (float*)(pool + 99328);                // [256][40] f32 (reuses xlsT/wt1)
  float* dbc          = (float*)(pool + 140288);               // [64][40] f32
  unsigned short* wot = (unsigned short*)(pool + 99328);       // [64][136] bf16 (w_out tile)

  const int tid = threadIdx.x;
  const int q = blockIdx.x;
  const int b = q / SEQ, n = q - b * SEQ;
  const float* xb = x + ((size_t)b * 64 * SEQ + n) * 128;

  // ---- load x (64x128) transposed -> xlsT[k][t] (bf16) ----
  for (int idx = tid; idx < 2048; idx += 256) {
    int w = idx >> 5, qd = (idx & 31) << 2;
    float4 v = *(const float4*)(xb + (size_t)w * SEQ * 128 + qd);
    xlsT[(qd + 0) * 68 + w] = f2bf(v.x);
    xlsT[(qd + 1) * 68 + w] = f2bf(v.y);
    xlsT[(qd + 2) * 68 + w] = f2bf(v.z);
    xlsT[(qd + 3) * 68 + w] = f2bf(v.w);
  }

  const int tg = tid & 15, cg = tid >> 4;   // t0 = tg*4, c0 = cg*8

  // ---- GEMM1: xz = x @ w_in (K=128, 512 cols in 4 tiles of 128) ----
  for (int ct = 0; ct < 4; ++ct) {
    __syncthreads();
    for (int idx = tid; idx < 16384; idx += 256) {
      int k = idx >> 7, c = idx & 127;
      wt1[k * 136 + c] = f2bf(w_in[k * 512 + ct * 128 + c]);
    }
    __syncthreads();
    float acc[4][8];
#pragma unroll
    for (int i = 0; i < 4; ++i)
#pragma unroll
      for (int j = 0; j < 8; ++j) acc[i][j] = 0.f;
    for (int k = 0; k < 128; ++k) {
      ushort4 xv = *(const ushort4*)&xlsT[k * 68 + tg * 4];
      ushort4 wa = *(const ushort4*)&wt1[k * 136 + cg * 8];
      ushort4 wb = *(const ushort4*)&wt1[k * 136 + cg * 8 + 4];
      float xf[4] = { bf2f(xv.x), bf2f(xv.y), bf2f(xv.z), bf2f(xv.w) };
      float wf[8] = { bf2f(wa.x), bf2f(wa.y), bf2f(wa.z), bf2f(wa.w),
                      bf2f(wb.x), bf2f(wb.y), bf2f(wb.z), bf2f(wb.w) };
#pragma unroll
      for (int i = 0; i < 4; ++i)
#pragma unroll
        for (int j = 0; j < 8; ++j) acc[i][j] = fmaf(xf[i], wf[j], acc[i][j]);
    }
#pragma unroll
    for (int i = 0; i < 4; ++i) {
      int t = tg * 4 + i;
#pragma unroll
      for (int j = 0; j < 8; ++j) {
        int c = ct * 128 + cg * 8 + j;
        if (c < 256) xcz[xidx(t, c)] = acc[i][j];
        else         zls[t * 256 + (c - 256)] = f2bf(acc[i][j]);
      }
    }
  }
  __syncthreads();

  // ---- causal depthwise conv (K=4, left pad 3) + bias + silu, in place ----
  {
    const int d = tid;
    float cw0 = conv_w[d*4+0], cw1 = conv_w[d*4+1], cw2 = conv_w[d*4+2], cw3 = conv_w[d*4+3];
    float cb = conv_b[d];
    float xm3 = 0.f, xm2 = 0.f, xm1 = 0.f;
    for (int t = 0; t < 64; ++t) {
      float xv = xcz[xidx(t, d)];
      float sacc = cw0*xm3 + cw1*xm2 + cw2*xm1 + cw3*xv + cb;
      xcz[xidx(t, d)] = siluf(sacc);
      xm3 = xm2; xm2 = xm1; xm1 = xv;
    }
  }
  __syncthreads();

  // ---- dbc = xc @ w_xp (K=256, 40 cols) ----
  for (int idx = tid; idx < 10240; idx += 256) wxp[idx] = w_xp[idx];
  __syncthreads();
  {
    const int jg = tid & 7, tgp = tid >> 3;   // 5 cols x 2 tokens per thread
    const int t0 = tgp * 2;
    float a0[5] = {0,0,0,0,0}, a1[5] = {0,0,0,0,0};
    for (int dd = 0; dd < 256; ++dd) {
      float x0 = xcz[xidx(t0, dd)];
      float x1 = xcz[xidx(t0 + 1, dd)];
      const float* wr = &wxp[dd * 40 + jg * 5];
#pragma unroll
      for (int m = 0; m < 5; ++m) {
        float wv = wr[m];
        a0[m] = fmaf(x0, wv, a0[m]);
        a1[m] = fmaf(x1, wv, a1[m]);
      }
    }
#pragma unroll
    for (int m = 0; m < 5; ++m) {
      dbc[t0 * 40 + jg * 5 + m]       = a0[m];
      dbc[(t0 + 1) * 40 + jg * 5 + m] = a1[m];
    }
  }
  __syncthreads();

  // ---- selective scan (thread = channel d), then gate, write back to xcz ----
  {
    const int d = tid;
    float dtw[8];
#pragma unroll
    for (int r = 0; r < 8; ++r) dtw[r] = dt_w[r * 256 + d];
    const float dtb = dt_b[d];
    float Af[16];
#pragma unroll
    for (int s = 0; s < 16; ++s) Af[s] = -__expf(Alog[d * 16 + s]);
    const float Dv = Dp[d];
    float h[16];
#pragma unroll
    for (int s = 0; s < 16; ++s) h[s] = 0.f;
    for (int t = 0; t < 64; ++t) {
      const float* dr = &dbc[t * 40];
      float dtv = dtb;
#pragma unroll
      for (int r = 0; r < 8; ++r) dtv = fmaf(dtw[r], dr[r], dtv);
      dtv = softplusf(dtv);
      float xv = xcz[xidx(t, d)];
      float cf = dtv * xv;
      float y = 0.f;
#pragma unroll
      for (int s = 0; s < 16; ++s) {
        float dA = __expf(dtv * Af[s]);
        h[s] = fmaf(dA, h[s], cf * dr[8 + s]);
        y = fmaf(h[s], dr[24 + s], y);
      }
      float zf = bf2f(zls[t * 256 + d]);
      xcz[xidx(t, d)] = (y + xv * Dv) * siluf(zf);
    }
  }
  __syncthreads();

  // ---- GEMM-out: out = gated (64x256) @ w_out (256x128) ----
  {
    float acc[4][8];
#pragma unroll
    for (int i = 0; i < 4; ++i)
#pragma unroll
      for (int j = 0; j < 8; ++j) acc[i][j] = 0.f;
    for (int kt = 0; kt < 4; ++kt) {
      __syncthreads();
      for (int idx = tid; idx < 8192; idx += 256) {
        int kk = idx >> 7, c = idx & 127;
        wot[kk * 136 + c] = f2bf(w_out[(kt * 64 + kk) * 128 + c]);
      }
      __syncthreads();
      for (int k4 = 0; k4 < 64; k4 += 4) {
        const int K0 = kt * 64 + k4;
        float4 xr0 = *(const float4*)&xcz[xidx(tg * 4 + 0, K0)];
        float4 xr1 = *(const float4*)&xcz[xidx(tg * 4 + 1, K0)];
        float4 xr2 = *(const float4*)&xcz[xidx(tg * 4 + 2, K0)];
        float4 xr3 = *(const float4*)&xcz[xidx(tg * 4 + 3, K0)];
#pragma unroll
        for (int kk = 0; kk < 4; ++kk) {
          ushort4 wa = *(const ushort4*)&wot[(k4 + kk) * 136 + cg * 8];
          ushort4 wb = *(const ushort4*)&wot[(k4 + kk) * 136 + cg * 8 + 4];
          float wf[8] = { bf2f(wa.x), bf2f(wa.y), bf2f(wa.z), bf2f(wa.w),
                          bf2f(wb.x), bf2f(wb.y), bf2f(wb.z), bf2f(wb.w) };
          float x0 = comp4(xr0, kk), x1 = comp4(xr1, kk);
          float x2 = comp4(xr2, kk), x3 = comp4(xr3, kk);
#pragma unroll
          for (int j = 0; j < 8; ++j) {
            acc[0][j] = fmaf(x0, wf[j], acc[0][j]);
            acc[1][j] = fmaf(x1, wf[j], acc[1][j]);
            acc[2][j] = fmaf(x2, wf[j], acc[2][j]);
            acc[3][j] = fmaf(x3, wf[j], acc[3][j]);
          }
        }
      }
    }
    size_t ob = (size_t)b * 64 * 512 * 128 + (size_t)(slot_base + n) * 128;
#pragma unroll
    for (int i = 0; i < 4; ++i) {
      int t = tg * 4 + i;
      float* dst = out + ob + (size_t)t * 65536 + cg * 8;
      *(float4*)dst       = make_float4(acc[i][0], acc[i][1], acc[i][2], acc[i][3]);
      *(float4*)(dst + 4) = make_float4(acc[i][4], acc[i][5], acc[i][6], acc[i][7]);
    }
  }
}

// ---------------------------------------------------------------------------
// mix: cat=[yn||yl]; cat += silu(cat @ mix_w + mix_b); in place on d_out.
// Block = 32 tokens of one (b,n) sequence.
// ---------------------------------------------------------------------------
__global__ __launch_bounds__(256) void mix_kernel(
    float* __restrict__ out, const float* __restrict__ mix_w,
    const float* __restrict__ mix_b)
{
  __shared__ __align__(16) char pool[36864 + 33792];
  float* catT = (float*)pool;                              // [256][36] f32
  unsigned short* mwt = (unsigned short*)(pool + 36864);   // [64][264] bf16

  const int tid = threadIdx.x;
  const int m0 = blockIdx.x * 32;
  const int bn = m0 >> 6, w0 = m0 & 63;
  const int b = bn >> 7, n = bn & 127;
  const size_t base_n = (((size_t)(b * 64 + w0)) * 512 + n) * 128;
  const size_t base_l = (((size_t)(b * 64 + w0)) * 512 + 384 + n) * 128;

  for (int idx = tid; idx < 2048; idx += 256) {
    int half = idx >> 10, r = idx & 1023;
    int tt = r >> 5, qd = (r & 31) << 2;
    const float* src = out + (half ? base_l : base_n) + (size_t)tt * 65536 + qd;
    float4 v = *(const float4*)src;
    catT[(half * 128 + qd + 0) * 36 + tt] = v.x;
    catT[(half * 128 + qd + 1) * 36 + tt] = v.y;
    catT[(half * 128 + qd + 2) * 36 + tt] = v.z;
    catT[(half * 128 + qd + 3) * 36 + tt] = v.w;
  }

  const int tg = tid & 7, cg = tid >> 3;   // t0 = tg*4, c0 = cg*8
  float acc[4][8];
#pragma unroll
  for (int i = 0; i < 4; ++i)
#pragma unroll
    for (int j = 0; j < 8; ++j) acc[i][j] = 0.f;

  for (int kt = 0; kt < 4; ++kt) {
    __syncthreads();
    for (int idx = tid; idx < 16384; idx += 256) {
      int kk = idx >> 8, c = idx & 255;
      mwt[kk * 264 + c] = f2bf(mix_w[(kt * 64 + kk) * 256 + c]);
    }
    __syncthreads();
    for (int k = 0; k < 64; ++k) {
      float4 xv = *(const float4*)&catT[(kt * 64 + k) * 36 + tg * 4];
      ushort4 wa = *(const ushort4*)&mwt[k * 264 + cg * 8];
      ushort4 wb = *(const ushort4*)&mwt[k * 264 + cg * 8 + 4];
      float wf[8] = { bf2f(wa.x), bf2f(wa.y), bf2f(wa.z), bf2f(wa.w),
                      bf2f(wb.x), bf2f(wb.y), bf2f(wb.z), bf2f(wb.w) };
#pragma unroll
      for (int j = 0; j < 8; ++j) {
        acc[0][j] = fmaf(xv.x, wf[j], acc[0][j]);
        acc[1][j] = fmaf(xv.y, wf[j], acc[1][j]);
        acc[2][j] = fmaf(xv.z, wf[j], acc[2][j]);
        acc[3][j] = fmaf(xv.w, wf[j], acc[3][j]);
      }
    }
  }
  const int half = (cg >= 16) ? 1 : 0;
  const int cc = (cg * 8) & 127;
  float bl[8];
#pragma unroll
  for (int j = 0; j < 8; ++j) bl[j] = mix_b[cg * 8 + j];
#pragma unroll
  for (int i = 0; i < 4; ++i) {
    int t = tg * 4 + i;
    float o[8];
#pragma unroll
    for (int j = 0; j < 8; ++j) {
      float v = acc[i][j] + bl[j];
      float orig = catT[(cg * 8 + j) * 36 + t];
      o[j] = orig + siluf(v);
    }
    float* dst = out + (half ? base_l : base_n) + (size_t)t * 65536 + cc;
    *(float4*)dst       = make_float4(o[0], o[1], o[2], o[3]);
    *(float4*)(dst + 4) = make_float4(o[4], o[5], o[6], o[7]);
  }
}

// ---------------------------------------------------------------------------
// residual + LayerNorm (an_g/an_b), in place on d_out. 64 tokens/block,
// 4 lanes per token.
// ---------------------------------------------------------------------------
__global__ __launch_bounds__(256) void res_ln(
    float* __restrict__ out, const float* __restrict__ xn,
    const float* __restrict__ xt, const float* __restrict__ xl,
    const float* __restrict__ g, const float* __restrict__ bb)
{
  const int tid = threadIdx.x;
  const int token = blockIdx.x * 64 + (tid >> 2);
  const int li = tid & 3;
  const int slot = token & 511;
  const int bw = token >> 9;
  const float* src; int s;
  if (slot < 128)      { s = 0; src = xn + ((size_t)bw * 128 + slot) * 128; }
  else if (slot < 384) { s = 1; src = xt + ((size_t)bw * 256 + (slot - 128)) * 128; }
  else                 { s = 2; src = xl + ((size_t)bw * 128 + (slot - 384)) * 128; }
  float* orow = out + (size_t)token * 128;
  float v[32];
  float sum = 0.f, sq = 0.f;
#pragma unroll
  for (int u = 0; u < 8; ++u) {
    int c = li * 32 + u * 4;
    float4 a = *(const float4*)(orow + c);
    float4 xx = *(const float4*)(src + c);
    float r0 = a.x + xx.x, r1 = a.y + xx.y, r2 = a.z + xx.z, r3 = a.w + xx.w;
    v[u*4+0] = r0; v[u*4+1] = r1; v[u*4+2] = r2; v[u*4+3] = r3;
    sum += r0 + r1 + r2 + r3;
    sq  += r0*r0 + r1*r1 + r2*r2 + r3*r3;
  }
  sum += __shfl_xor(sum, 1); sum += __shfl_xor(sum, 2);
  sq  += __shfl_xor(sq, 1);  sq  += __shfl_xor(sq, 2);
  float mean = sum * (1.f / 128.f);
  float var = sq * (1.f / 128.f) - mean * mean;
  float rs = rsqrtf(var + 1e-5f);
  const float* G = g + s * 128;
  const float* Bv = bb + s * 128;
#pragma unroll
  for (int u = 0; u < 8; ++u) {
    int c = li * 32 + u * 4;
    float4 gg = *(const float4*)(G + c);
    float4 bv = *(const float4*)(Bv + c);
    float4 o;
    o.x = (v[u*4+0] - mean) * rs * gg.x + bv.x;
    o.y = (v[u*4+1] - mean) * rs * gg.y + bv.y;
    o.z = (v[u*4+2] - mean) * rs * gg.z + bv.z;
    o.w = (v[u*4+3] - mean) * rs * gg.w + bv.w;
    *(float4*)(orow + c) = o;
  }
}

// ---------------------------------------------------------------------------
// FFN: h = leaky_relu(x@ff1+b1, .01); out = LN(h@ff2 + b2 + x). In place.
// Block = 64 tokens (uniform stream).
// ---------------------------------------------------------------------------
__global__ __launch_bounds__(256) void ffn_kernel(
    float* __restrict__ out,
    const float* __restrict__ w1, const float* __restrict__ b1,
    const float* __restrict__ w2, const float* __restrict__ b2,
    const float* __restrict__ g, const float* __restrict__ bb)
{
  __shared__ __align__(16) char pool[18432 + 73728 + 34816];
  unsigned short* xT = (unsigned short*)pool;             // [128][72] bf16
  unsigned short* hT = (unsigned short*)(pool + 18432);   // [512][72] bf16
  unsigned short* wt = (unsigned short*)(pool + 92160);   // [128][136] bf16
  float* ep          = (float*)(pool + 92160);            // [64][132] f32

  const int tid = threadIdx.x;
  const int tok0 = blockIdx.x * 64;
  const int slot0 = tok0 & 511;
  const int s = slot0 < 128 ? 0 : (slot0 < 384 ? 1 : 2);
  const float* W1 = w1 + (size_t)s * 65536;
  const float* B1 = b1 + s * 512;
  const float* W2 = w2 + (size_t)s * 65536;
  const float* B2 = b2 + s * 128;
  const float* G = g + s * 128;
  const float* Bb = bb + s * 128;

  for (int idx = tid; idx < 2048; idx += 256) {
    int tt = idx >> 5, qd = (idx & 31) << 2;
    float4 v = *(const float4*)(out + (size_t)(tok0 + tt) * 128 + qd);
    xT[(qd + 0) * 72 + tt] = f2bf(v.x);
    xT[(qd + 1) * 72 + tt] = f2bf(v.y);
    xT[(qd + 2) * 72 + tt] = f2bf(v.z);
    xT[(qd + 3) * 72 + tt] = f2bf(v.w);
  }

  const int tg = tid & 15, cg = tid >> 4;
  // GEMM1 (K=128, 512 cols in 4 tiles)
  for (int ct = 0; ct < 4; ++ct) {
    __syncthreads();
    for (int idx = tid; idx < 16384; idx += 256) {
      int k = idx >> 7, c = idx & 127;
      wt[k * 136 + c] = f2bf(W1[k * 512 + ct * 128 + c]);
    }
    __syncthreads();
    float acc[4][8];
#pragma unroll
    for (int i = 0; i < 4; ++i)
#pragma unroll
      for (int j = 0; j < 8; ++j) acc[i][j] = 0.f;
    for (int k = 0; k < 128; ++k) {
      ushort4 xv = *(const ushort4*)&xT[k * 72 + tg * 4];
      ushort4 wa = *(const ushort4*)&wt[k * 136 + cg * 8];
      ushort4 wb = *(const ushort4*)&wt[k * 136 + cg * 8 + 4];
      float xf[4] = { bf2f(xv.x), bf2f(xv.y), bf2f(xv.z), bf2f(xv.w) };
      float wf[8] = { bf2f(wa.x), bf2f(wa.y), bf2f(wa.z), bf2f(wa.w),
                      bf2f(wb.x), bf2f(wb.y), bf2f(wb.z), bf2f(wb.w) };
#pragma unroll
      for (int i = 0; i < 4; ++i)
#pragma unroll
        for (int j = 0; j < 8; ++j) acc[i][j] = fmaf(xf[i], wf[j], acc[i][j]);
    }
#pragma unroll
    for (int i = 0; i < 4; ++i) {
#pragma unroll
      for (int j = 0; j < 8; ++j) {
        int c = ct * 128 + cg * 8 + j;
        float v = acc[i][j] + B1[c];
        v = v > 0.f ? v : 0.01f * v;
        hT[c * 72 + tg * 4 + i] = f2bf(v);
      }
    }
  }
  __syncthreads();

  // GEMM2 (K=512 in 8 k-tiles, 128 cols)
  float acc2[4][8];
#pragma unroll
  for (int i = 0; i < 4; ++i)
#pragma unroll
    for (int j = 0; j < 8; ++j) acc2[i][j] = 0.f;
  for (int kt = 0; kt < 8; ++kt) {
    __syncthreads();
    for (int idx = tid; idx < 8192; idx += 256) {
      int kk = idx >> 7, c = idx & 127;
      wt[kk * 136 + c] = f2bf(W2[(kt * 64 + kk) * 128 + c]);
    }
    __syncthreads();
    for (int k = 0; k < 64; ++k) {
      ushort4 xv = *(const ushort4*)&hT[(kt * 64 + k) * 72 + tg * 4];
      ushort4 wa = *(const ushort4*)&wt[k * 136 + cg * 8];
      ushort4 wb = *(const ushort4*)&wt[k * 136 + cg * 8 + 4];
      float xf[4] = { bf2f(xv.x), bf2f(xv.y), bf2f(xv.z), bf2f(xv.w) };
      float wf[8] = { bf2f(wa.x), bf2f(wa.y), bf2f(wa.z), bf2f(wa.w),
                      bf2f(wb.x), bf2f(wb.y), bf2f(wb.z), bf2f(wb.w) };
#pragma unroll
      for (int i = 0; i < 4; ++i)
#pragma unroll
        for (int j = 0; j < 8; ++j) acc2[i][j] = fmaf(xf[i], wf[j], acc2[i][j]);
    }
  }
  __syncthreads();
  // epilogue: v = acc2 + b2 + x  (staged to ep, then LN)
#pragma unroll
  for (int i = 0; i < 4; ++i) {
    int t = tg * 4 + i;
#pragma unroll
    for (int j = 0; j < 8; ++j) {
      int c = cg * 8 + j;
      ep[t * 132 + c] = acc2[i][j] + B2[c] + bf2f(xT[c * 72 + t]);
    }
  }
  __syncthreads();
  {
    const int tt = tid >> 2, li = tid & 3;
    float v[32];
    float sum = 0.f, sq = 0.f;
#pragma unroll
    for (int u = 0; u < 8; ++u) {
      int c = li * 32 + u * 4;
      float4 r = *(const float4*)&ep[tt * 132 + c];
      v[u*4+0] = r.x; v[u*4+1] = r.y; v[u*4+2] = r.z; v[u*4+3] = r.w;
      sum += r.x + r.y + r.z + r.w;
      sq  += r.x*r.x + r.y*r.y + r.z*r.z + r.w*r.w;
    }
    sum += __shfl_xor(sum, 1); sum += __shfl_xor(sum, 2);
    sq  += __shfl_xor(sq, 1);  sq  += __shfl_xor(sq, 2);
    float mean = sum * (1.f / 128.f);
    float var = sq * (1.f / 128.f) - mean * mean;
    float rs = rsqrtf(var + 1e-5f);
    float* orow = out + (size_t)(tok0 + tt) * 128;
#pragma unroll
    for (int u = 0; u < 8; ++u) {
      int c = li * 32 + u * 4;
      float4 gg = *(const float4*)(G + c);
      float4 bv = *(const float4*)(Bb + c);
      float4 o;
      o.x = (v[u*4+0] - mean) * rs * gg.x + bv.x;
      o.y = (v[u*4+1] - mean) * rs * gg.y + bv.y;
      o.z = (v[u*4+2] - mean) * rs * gg.z + bv.z;
      o.w = (v[u*4+3] - mean) * rs * gg.w + bv.w;
      *(float4*)(orow + c) = o;
    }
  }
}

extern "C" void kernel_launch(void* const* d_in, const int* in_sizes, int n_in,
                              void* d_out, int out_size, void* d_ws, size_t ws_size,
                              hipStream_t stream) {
  (void)in_sizes; (void)n_in; (void)out_size; (void)d_ws; (void)ws_size;
  const float* x_node  = (const float*)d_in[0];
  const float* x_trace = (const float*)d_in[1];
  const float* x_log   = (const float*)d_in[2];
  const float* mp_in     = (const float*)d_in[3];
  const float* mp_conv_w = (const float*)d_in[4];
  const float* mp_conv_b = (const float*)d_in[5];
  const float* mp_xproj  = (const float*)d_in[6];
  const float* mp_dt_w   = (const float*)d_in[7];
  const float* mp_dt_b   = (const float*)d_in[8];
  const float* mp_Alog   = (const float*)d_in[9];
  const float* mp_D      = (const float*)d_in[10];
  const float* mp_out    = (const float*)d_in[11];
  const float* mix_w = (const float*)d_in[12];
  const float* mix_b = (const float*)d_in[13];
  const float* an_g  = (const float*)d_in[14];
  const float* an_b  = (const float*)d_in[15];
  const float* ff1_w = (const float*)d_in[16];
  const float* ff1_b = (const float*)d_in[17];
  const float* ff2_w = (const float*)d_in[18];
  const float* ff2_b = (const float*)d_in[19];
  const float* fln_g = (const float*)d_in[20];
  const float* fln_b = (const float*)d_in[21];
  float* out = (float*)d_out;

  for (int s = 0; s < 3; ++s) {
    const float* xp = s == 0 ? x_node : (s == 1 ? x_trace : x_log);
    int SEQ  = (s == 1) ? 256 : 128;
    int slot = (s == 0) ? 0 : (s == 1 ? 128 : 384);
    int grid = 8 * SEQ;
    mamba_front<<<grid, 256, 0, stream>>>(
        xp, SEQ, slot,
        mp_in + (size_t)s * 65536, mp_conv_w + (size_t)s * 1024,
        mp_conv_b + (size_t)s * 256, mp_xproj + (size_t)s * 10240,
        mp_dt_w + (size_t)s * 2048, mp_dt_b + (size_t)s * 256,
        mp_Alog + (size_t)s * 4096, mp_D + (size_t)s * 256,
        mp_out + (size_t)s * 32768, out);
  }
  mix_kernel<<<2048, 256, 0, stream>>>(out, mix_w, mix_b);
  res_ln<<<4096, 256, 0, stream>>>(out, x_node, x_trace, x_log, an_g, an_b);
  ffn_kernel<<<4096, 256, 0, stream>>>(out, ff1_w, ff1_b, ff2_w, ff2_b, fln_g, fln_b);
}

// Round 2
// 1171.034 us; speedup vs baseline: 3.6972x; 3.6972x over previous
//
#include <hip/hip_runtime.h>

#define DEV __device__ __forceinline__

typedef __attribute__((ext_vector_type(8))) short bf16x8;
typedef __attribute__((ext_vector_type(4))) float f32x4;

DEV f32x4 MF(bf16x8 a, bf16x8 b, f32x4 c) {
  return __builtin_amdgcn_mfma_f32_16x16x32_bf16(a, b, c, 0, 0, 0);
}

DEV float bf2f(unsigned short u) {
  union { unsigned int i; float f; } v; v.i = ((unsigned int)u) << 16; return v.f;
}
DEV unsigned short f2bf(float f) {
  union { float f; unsigned int i; } v; v.f = f;
  unsigned int x = v.i;
  return (unsigned short)((x + 0x7fffu + ((x >> 16) & 1u)) >> 16);
}
DEV float softplusf(float v) { return v > 20.f ? v : log1pf(__expf(v)); }
DEV float siluf(float v) { return v / (1.f + __expf(-v)); }

// ws layout (bf16 element offsets)
#define WS_WINT   0        // 3 x [512][128]
#define WS_WXPT   196608   // 3 x [48][256] (cols 40..47 zero)
#define WS_WOUTT  233472   // 3 x [128][256]
#define WS_FF1T   331776   // 3 x [512][128]
#define WS_FF2T   528384   // 3 x [128][512]
#define WS_MIXT   724992   // [256][256]
#define WS_TOTAL  790528

// ---------------------------------------------------------------------------
// prep: transpose+convert all weight matrices into ws as bf16 [N][K]
// ---------------------------------------------------------------------------
__global__ __launch_bounds__(256) void prep_kernel(
    const float* __restrict__ w_in, const float* __restrict__ w_xp,
    const float* __restrict__ w_out, const float* __restrict__ ff1,
    const float* __restrict__ ff2, const float* __restrict__ mixw,
    unsigned short* __restrict__ ws)
{
  int idx = blockIdx.x * 256 + threadIdx.x;
  if (idx >= WS_TOTAL) return;
  float v;
  if (idx < WS_WXPT) {              // w_inT [s][512][128]
    int j = idx, s = j / 65536, r = j % 65536, n = r >> 7, k = r & 127;
    v = w_in[s * 65536 + k * 512 + n];
  } else if (idx < WS_WOUTT) {      // w_xpT [s][48][256]
    int j = idx - WS_WXPT, s = j / 12288, r = j % 12288, n = r >> 8, k = r & 255;
    v = (n < 40) ? w_xp[s * 10240 + k * 40 + n] : 0.f;
  } else if (idx < WS_FF1T) {       // w_outT [s][128][256]
    int j = idx - WS_WOUTT, s = j / 32768, r = j % 32768, n = r >> 8, k = r & 255;
    v = w_out[s * 32768 + k * 128 + n];
  } else if (idx < WS_FF2T) {       // ff1T [s][512][128]
    int j = idx - WS_FF1T, s = j / 65536, r = j % 65536, n = r >> 7, k = r & 127;
    v = ff1[s * 65536 + k * 512 + n];
  } else if (idx < WS_MIXT) {       // ff2T [s][128][512]
    int j = idx - WS_FF2T, s = j / 65536, r = j % 65536, n = r >> 9, k = r & 511;
    v = ff2[s * 65536 + k * 128 + n];
  } else {                          // mixT [256][256]
    int j = idx - WS_MIXT, n = j >> 8, k = j & 255;
    v = mixw[k * 256 + n];
  }
  ws[idx] = f2bf(v);
}

// ---------------------------------------------------------------------------
// Fused mamba front with MFMA GEMMs. One block = one sequence (W=64).
// ---------------------------------------------------------------------------
__global__ __launch_bounds__(256, 2) void mamba_front(
    const float* __restrict__ x, int SEQ, int slot_base,
    const unsigned short* __restrict__ w_inT, const float* __restrict__ conv_w,
    const float* __restrict__ conv_b, const unsigned short* __restrict__ w_xpT,
    const float* __restrict__ dt_w, const float* __restrict__ dt_b,
    const float* __restrict__ Alog, const float* __restrict__ Dp,
    const unsigned short* __restrict__ w_outT, float* __restrict__ out)
{
  __shared__ __attribute__((aligned(16))) unsigned short xcz[64 * 512]; // [t][n^swz]
  __shared__ __attribute__((aligned(16))) char aux[16384];
  unsigned short* xs = (unsigned short*)aux;   // [64][128] bf16 swizzled
  float* dbc = (float*)aux;                    // [64][48] f32 (after GEMM1 done)

  const int tid = threadIdx.x;
  const int lane = tid & 63;
  const int wv = tid >> 6;
  const int lr = lane & 15;
  const int kg = lane >> 4;
  const int q = blockIdx.x;
  const int b = q / SEQ, n = q - b * SEQ;
  const float* xb = x + ((size_t)b * 64 * SEQ + n) * 128;

  // stage x -> xs (bf16, XOR-swizzled)
  for (int idx = tid; idx < 2048; idx += 256) {
    int t = idx >> 5, qd = (idx & 31) << 2;
    float4 v = *(const float4*)(xb + (size_t)t * SEQ * 128 + qd);
    uint2 p;
    p.x = f2bf(v.x) | ((unsigned int)f2bf(v.y) << 16);
    p.y = f2bf(v.z) | ((unsigned int)f2bf(v.w) << 16);
    *(uint2*)(&xs[t * 128 + (qd ^ ((t & 7) << 3))]) = p;
  }
  __syncthreads();

  // GEMM1 (swapped): xz^T[n][t] = w_inT[n][:] . x[t][:]
  {
    bf16x8 bx[4][4];
#pragma unroll
    for (int jt = 0; jt < 4; ++jt)
#pragma unroll
      for (int ks = 0; ks < 4; ++ks) {
        int t = jt * 16 + lr;
        bx[jt][ks] = *(const bf16x8*)(&xs[t * 128 + ((ks * 32 + kg * 8) ^ ((t & 7) << 3))]);
      }
    const int nb = wv * 128;
#pragma unroll
    for (int at = 0; at < 8; ++at) {
      bf16x8 av[4];
      int arow = nb + at * 16 + lr;
#pragma unroll
      for (int ks = 0; ks < 4; ++ks)
        av[ks] = *(const bf16x8*)(w_inT + arow * 128 + ks * 32 + kg * 8);
#pragma unroll
      for (int jt = 0; jt < 4; ++jt) {
        f32x4 c = {0.f, 0.f, 0.f, 0.f};
#pragma unroll
        for (int ks = 0; ks < 4; ++ks) c = MF(av[ks], bx[jt][ks], c);
        int t = jt * 16 + lr;
        int n0 = nb + at * 16 + kg * 4;
        uint2 p;
        p.x = f2bf(c[0]) | ((unsigned int)f2bf(c[1]) << 16);
        p.y = f2bf(c[2]) | ((unsigned int)f2bf(c[3]) << 16);
        *(uint2*)(&xcz[t * 512 + (n0 ^ ((t & 7) << 3))]) = p;
      }
    }
  }
  __syncthreads();

  // causal depthwise conv + bias + silu, in place on xc region (thread = d)
  {
    const int d = tid;
    float cw0 = conv_w[d * 4 + 0], cw1 = conv_w[d * 4 + 1];
    float cw2 = conv_w[d * 4 + 2], cw3 = conv_w[d * 4 + 3];
    float cb = conv_b[d];
    float xm3 = 0.f, xm2 = 0.f, xm1 = 0.f;
    for (int t = 0; t < 64; ++t) {
      int e = t * 512 + (d ^ ((t & 7) << 3));
      float xv = bf2f(xcz[e]);
      float sv = fmaf(cw0, xm3, fmaf(cw1, xm2, fmaf(cw2, xm1, fmaf(cw3, xv, cb))));
      xcz[e] = f2bf(siluf(sv));
      xm3 = xm2; xm2 = xm1; xm1 = xv;
    }
  }
  __syncthreads();

  // x_proj via MFMA: dbc[t][c] = xc[t][:] . w_xpT[c][:]   (wave = t-tile)
  {
    bf16x8 av[8];
    int ta = wv * 16 + lr;
#pragma unroll
    for (int ks = 0; ks < 8; ++ks)
      av[ks] = *(const bf16x8*)(&xcz[ta * 512 + ((ks * 32 + kg * 8) ^ ((ta & 7) << 3))]);
#pragma unroll
    for (int ct = 0; ct < 3; ++ct) {
      f32x4 c = {0.f, 0.f, 0.f, 0.f};
#pragma unroll
      for (int ks = 0; ks < 8; ++ks) {
        bf16x8 bv = *(const bf16x8*)(w_xpT + (ct * 16 + lr) * 256 + ks * 32 + kg * 8);
        c = MF(av[ks], bv, c);
      }
      int tt = wv * 16 + kg * 4;
#pragma unroll
      for (int r = 0; r < 4; ++r)
        dbc[(tt + r) * 48 + ct * 16 + lr] = c[r];
    }
  }
  __syncthreads();

  // selective scan + gate (thread = d), writes gated y back into xc slots
  {
    const int d = tid;
    float dtw[8];
#pragma unroll
    for (int r = 0; r < 8; ++r) dtw[r] = dt_w[r * 256 + d];
    const float dtb = dt_b[d];
    float Af[16];
#pragma unroll
    for (int s = 0; s < 16; ++s) Af[s] = -__expf(Alog[d * 16 + s]);
    const float Dv = Dp[d];
    float h[16];
#pragma unroll
    for (int s = 0; s < 16; ++s) h[s] = 0.f;
    for (int t = 0; t < 64; ++t) {
      const float* dr = &dbc[t * 48];
      float dtv = dtb;
#pragma unroll
      for (int r = 0; r < 8; ++r) dtv = fmaf(dtw[r], dr[r], dtv);
      dtv = softplusf(dtv);
      int e = t * 512 + (d ^ ((t & 7) << 3));
      float xv = bf2f(xcz[e]);
      float zf = bf2f(xcz[t * 512 + ((256 + d) ^ ((t & 7) << 3))]);
      float cf = dtv * xv;
      float y = 0.f;
#pragma unroll
      for (int s = 0; s < 16; ++s) {
        float dA = __expf(dtv * Af[s]);
        h[s] = fmaf(dA, h[s], cf * dr[8 + s]);
        y = fmaf(h[s], dr[24 + s], y);
      }
      xcz[e] = f2bf((y + xv * Dv) * siluf(zf));
    }
  }
  __syncthreads();

  // GEMM-out via MFMA: out[t][c] = yg[t][:] . w_outT[c][:]  (wave = t-tile)
  {
    bf16x8 av[8];
    int ta = wv * 16 + lr;
#pragma unroll
    for (int ks = 0; ks < 8; ++ks)
      av[ks] = *(const bf16x8*)(&xcz[ta * 512 + ((ks * 32 + kg * 8) ^ ((ta & 7) << 3))]);
    size_t ob = (size_t)b * 64 * 512 * 128 + (size_t)(slot_base + n) * 128;
#pragma unroll
    for (int ct = 0; ct < 8; ++ct) {
      f32x4 c = {0.f, 0.f, 0.f, 0.f};
#pragma unroll
      for (int ks = 0; ks < 8; ++ks) {
        bf16x8 bv = *(const bf16x8*)(w_outT + (ct * 16 + lr) * 256 + ks * 32 + kg * 8);
        c = MF(av[ks], bv, c);
      }
      int tt = wv * 16 + kg * 4;
      int cc = ct * 16 + lr;
#pragma unroll
      for (int r = 0; r < 4; ++r)
        out[ob + (size_t)(tt + r) * 65536 + cc] = c[r];
    }
  }
}

// ---------------------------------------------------------------------------
// mix: cat=[yn||yl]; cat += silu(cat @ mix_w + mix_b). One block = one (b,n),
// 64 w-tokens. MFMA.
// ---------------------------------------------------------------------------
__global__ __launch_bounds__(256, 4) void mix_kernel(
    float* __restrict__ out, const unsigned short* __restrict__ mixT,
    const float* __restrict__ mix_b)
{
  __shared__ __attribute__((aligned(16))) unsigned short cs[64 * 256];

  const int tid = threadIdx.x;
  const int lane = tid & 63;
  const int wv = tid >> 6;
  const int lr = lane & 15;
  const int kg = lane >> 4;
  const int bn = blockIdx.x;
  const int b = bn >> 7, n = bn & 127;
  const size_t base_n = (((size_t)b * 64) * 512 + n) * 128;
  const size_t base_l = (((size_t)b * 64) * 512 + 384 + n) * 128;

  for (int idx = tid; idx < 4096; idx += 256) {
    int t = idx >> 6, r = idx & 63;
    int half = r >> 5, qd = (r & 31) << 2;
    const float* src = out + (half ? base_l : base_n) + (size_t)t * 65536 + qd;
    float4 v = *(const float4*)src;
    int col = half * 128 + qd;
    uint2 p;
    p.x = f2bf(v.x) | ((unsigned int)f2bf(v.y) << 16);
    p.y = f2bf(v.z) | ((unsigned int)f2bf(v.w) << 16);
    *(uint2*)(&cs[t * 256 + (col ^ ((t & 7) << 3))]) = p;
  }
  __syncthreads();

  bf16x8 av[8];
  int ta = wv * 16 + lr;
#pragma unroll
  for (int ks = 0; ks < 8; ++ks)
    av[ks] = *(const bf16x8*)(&cs[ta * 256 + ((ks * 32 + kg * 8) ^ ((ta & 7) << 3))]);

#pragma unroll
  for (int ct = 0; ct < 16; ++ct) {
    f32x4 c = {0.f, 0.f, 0.f, 0.f};
#pragma unroll
    for (int ks = 0; ks < 8; ++ks) {
      bf16x8 bv = *(const bf16x8*)(mixT + (ct * 16 + lr) * 256 + ks * 32 + kg * 8);
      c = MF(av[ks], bv, c);
    }
    int col = ct * 16 + lr;
    float bcol = mix_b[col];
    int tt = wv * 16 + kg * 4;
#pragma unroll
    for (int r = 0; r < 4; ++r) {
      int t = tt + r;
      float orig = bf2f(cs[t * 256 + (col ^ ((t & 7) << 3))]);
      float o = orig + siluf(c[r] + bcol);
      float* dst = out + (col < 128 ? base_n : base_l) + (size_t)t * 65536 + (col & 127);
      *dst = o;
    }
  }
}

// ---------------------------------------------------------------------------
// residual + LayerNorm (an_g/an_b), in place on d_out.
// ---------------------------------------------------------------------------
__global__ __launch_bounds__(256) void res_ln(
    float* __restrict__ out, const float* __restrict__ xn,
    const float* __restrict__ xt, const float* __restrict__ xl,
    const float* __restrict__ g, const float* __restrict__ bb)
{
  const int tid = threadIdx.x;
  const int token = blockIdx.x * 64 + (tid >> 2);
  const int li = tid & 3;
  const int slot = token & 511;
  const int bw = token >> 9;
  const float* src; int s;
  if (slot < 128)      { s = 0; src = xn + ((size_t)bw * 128 + slot) * 128; }
  else if (slot < 384) { s = 1; src = xt + ((size_t)bw * 256 + (slot - 128)) * 128; }
  else                 { s = 2; src = xl + ((size_t)bw * 128 + (slot - 384)) * 128; }
  float* orow = out + (size_t)token * 128;
  float v[32];
  float sum = 0.f, sq = 0.f;
#pragma unroll
  for (int u = 0; u < 8; ++u) {
    int c = li * 32 + u * 4;
    float4 a = *(const float4*)(orow + c);
    float4 xx = *(const float4*)(src + c);
    float r0 = a.x + xx.x, r1 = a.y + xx.y, r2 = a.z + xx.z, r3 = a.w + xx.w;
    v[u*4+0] = r0; v[u*4+1] = r1; v[u*4+2] = r2; v[u*4+3] = r3;
    sum += r0 + r1 + r2 + r3;
    sq  += r0*r0 + r1*r1 + r2*r2 + r3*r3;
  }
  sum += __shfl_xor(sum, 1); sum += __shfl_xor(sum, 2);
  sq  += __shfl_xor(sq, 1);  sq  += __shfl_xor(sq, 2);
  float mean = sum * (1.f / 128.f);
  float var = sq * (1.f / 128.f) - mean * mean;
  float rs = rsqrtf(var + 1e-5f);
  const float* G = g + s * 128;
  const float* Bv = bb + s * 128;
#pragma unroll
  for (int u = 0; u < 8; ++u) {
    int c = li * 32 + u * 4;
    float4 gg = *(const float4*)(G + c);
    float4 bv = *(const float4*)(Bv + c);
    float4 o;
    o.x = (v[u*4+0] - mean) * rs * gg.x + bv.x;
    o.y = (v[u*4+1] - mean) * rs * gg.y + bv.y;
    o.z = (v[u*4+2] - mean) * rs * gg.z + bv.z;
    o.w = (v[u*4+3] - mean) * rs * gg.w + bv.w;
    *(float4*)(orow + c) = o;
  }
}

// ---------------------------------------------------------------------------
// FFN via MFMA: h = leaky_relu(x@ff1+b1); out = LN(h@ff2 + b2 + x). In place.
// Block = 64 tokens (uniform stream).
// ---------------------------------------------------------------------------
__global__ __launch_bounds__(256, 2) void ffn_kernel(
    float* __restrict__ out,
    const unsigned short* __restrict__ ff1T, const float* __restrict__ b1,
    const unsigned short* __restrict__ ff2T, const float* __restrict__ b2,
    const float* __restrict__ g, const float* __restrict__ bb)
{
  __shared__ __attribute__((aligned(16))) unsigned short hT[64 * 512];
  __shared__ __attribute__((aligned(16))) unsigned short xs[64 * 128];

  const int tid = threadIdx.x;
  const int lane = tid & 63;
  const int wv = tid >> 6;
  const int lr = lane & 15;
  const int kg = lane >> 4;
  const int tok0 = blockIdx.x * 64;
  const int slot0 = tok0 & 511;
  const int s = slot0 < 128 ? 0 : (slot0 < 384 ? 1 : 2);
  const unsigned short* F1 = ff1T + (size_t)s * 65536;
  const unsigned short* F2 = ff2T + (size_t)s * 65536;
  const float* B1 = b1 + s * 512;
  const float* B2 = b2 + s * 128;
  const float* G = g + s * 128;
  const float* Bb = bb + s * 128;

  for (int idx = tid; idx < 2048; idx += 256) {
    int t = idx >> 5, qd = (idx & 31) << 2;
    float4 v = *(const float4*)(out + (size_t)(tok0 + t) * 128 + qd);
    uint2 p;
    p.x = f2bf(v.x) | ((unsigned int)f2bf(v.y) << 16);
    p.y = f2bf(v.z) | ((unsigned int)f2bf(v.w) << 16);
    *(uint2*)(&xs[t * 128 + (qd ^ ((t & 7) << 3))]) = p;
  }
  __syncthreads();

  // GEMM1 (swapped): h^T[n][t] = ff1T[n][:] . x[t][:], +b1, leaky-relu
  {
    bf16x8 bx[4][4];
#pragma unroll
    for (int jt = 0; jt < 4; ++jt)
#pragma unroll
      for (int ks = 0; ks < 4; ++ks) {
        int t = jt * 16 + lr;
        bx[jt][ks] = *(const bf16x8*)(&xs[t * 128 + ((ks * 32 + kg * 8) ^ ((t & 7) << 3))]);
      }
    const int nb = wv * 128;
#pragma unroll
    for (int at = 0; at < 8; ++at) {
      bf16x8 av[4];
      int arow = nb + at * 16 + lr;
#pragma unroll
      for (int ks = 0; ks < 4; ++ks)
        av[ks] = *(const bf16x8*)(F1 + arow * 128 + ks * 32 + kg * 8);
      float4 bias = *(const float4*)(B1 + nb + at * 16 + kg * 4);
#pragma unroll
      for (int jt = 0; jt < 4; ++jt) {
        f32x4 c = {0.f, 0.f, 0.f, 0.f};
#pragma unroll
        for (int ks = 0; ks < 4; ++ks) c = MF(av[ks], bx[jt][ks], c);
        float v0 = c[0] + bias.x; v0 = v0 > 0.f ? v0 : 0.01f * v0;
        float v1 = c[1] + bias.y; v1 = v1 > 0.f ? v1 : 0.01f * v1;
        float v2 = c[2] + bias.z; v2 = v2 > 0.f ? v2 : 0.01f * v2;
        float v3 = c[3] + bias.w; v3 = v3 > 0.f ? v3 : 0.01f * v3;
        int t = jt * 16 + lr;
        int n0 = nb + at * 16 + kg * 4;
        uint2 p;
        p.x = f2bf(v0) | ((unsigned int)f2bf(v1) << 16);
        p.y = f2bf(v2) | ((unsigned int)f2bf(v3) << 16);
        *(uint2*)(&hT[t * 512 + (n0 ^ ((t & 7) << 3))]) = p;
      }
    }
  }
  __syncthreads();

  // GEMM2: out[t][c] = h[t][:] . ff2T[c][:]   (wave = t-tile), + LN epilogue
  {
    bf16x8 av[16];
    int ta = wv * 16 + lr;
#pragma unroll
    for (int ks = 0; ks < 16; ++ks)
      av[ks] = *(const bf16x8*)(&hT[ta * 512 + ((ks * 32 + kg * 8) ^ ((ta & 7) << 3))]);
    f32x4 acc[8];
#pragma unroll
    for (int ct = 0; ct < 8; ++ct) {
      f32x4 c = {0.f, 0.f, 0.f, 0.f};
#pragma unroll
      for (int ks = 0; ks < 16; ++ks) {
        bf16x8 bv = *(const bf16x8*)(F2 + (ct * 16 + lr) * 512 + ks * 32 + kg * 8);
        c = MF(av[ks], bv, c);
      }
      acc[ct] = c;
    }

    float v[8][4];
    float sum[4] = {0.f, 0.f, 0.f, 0.f}, sq[4] = {0.f, 0.f, 0.f, 0.f};
    const int trow = wv * 16 + kg * 4;
#pragma unroll
    for (int ct = 0; ct < 8; ++ct) {
      int col = ct * 16 + lr;
      float b2c = B2[col];
#pragma unroll
      for (int r = 0; r < 4; ++r) {
        int t = trow + r;
        float xr = bf2f(xs[t * 128 + (col ^ ((t & 7) << 3))]);
        float val = acc[ct][r] + b2c + xr;
        v[ct][r] = val;
        sum[r] += val; sq[r] += val * val;
      }
    }
    float mn[4], rstd[4];
#pragma unroll
    for (int r = 0; r < 4; ++r) {
      float s1 = sum[r], s2 = sq[r];
      s1 += __shfl_xor(s1, 1); s2 += __shfl_xor(s2, 1);
      s1 += __shfl_xor(s1, 2); s2 += __shfl_xor(s2, 2);
      s1 += __shfl_xor(s1, 4); s2 += __shfl_xor(s2, 4);
      s1 += __shfl_xor(s1, 8); s2 += __shfl_xor(s2, 8);
      float mean = s1 * (1.f / 128.f);
      float var = s2 * (1.f / 128.f) - mean * mean;
      mn[r] = mean;
      rstd[r] = rsqrtf(var + 1e-5f);
    }
#pragma unroll
    for (int ct = 0; ct < 8; ++ct) {
      int col = ct * 16 + lr;
      float gc = G[col], bc = Bb[col];
#pragma unroll
      for (int r = 0; r < 4; ++r)
        out[(size_t)(tok0 + trow + r) * 128 + col] = (v[ct][r] - mn[r]) * rstd[r] * gc + bc;
    }
  }
}

extern "C" void kernel_launch(void* const* d_in, const int* in_sizes, int n_in,
                              void* d_out, int out_size, void* d_ws, size_t ws_size,
                              hipStream_t stream) {
  (void)in_sizes; (void)n_in; (void)out_size; (void)ws_size;
  const float* x_node  = (const float*)d_in[0];
  const float* x_trace = (const float*)d_in[1];
  const float* x_log   = (const float*)d_in[2];
  const float* mp_in     = (const float*)d_in[3];
  const float* mp_conv_w = (const float*)d_in[4];
  const float* mp_conv_b = (const float*)d_in[5];
  const float* mp_xproj  = (const float*)d_in[6];
  const float* mp_dt_w   = (const float*)d_in[7];
  const float* mp_dt_b   = (const float*)d_in[8];
  const float* mp_Alog   = (const float*)d_in[9];
  const float* mp_D      = (const float*)d_in[10];
  const float* mp_out    = (const float*)d_in[11];
  const float* mix_w = (const float*)d_in[12];
  const float* mix_b = (const float*)d_in[13];
  const float* an_g  = (const float*)d_in[14];
  const float* an_b  = (const float*)d_in[15];
  const float* ff1_w = (const float*)d_in[16];
  const float* ff1_b = (const float*)d_in[17];
  const float* ff2_w = (const float*)d_in[18];
  const float* ff2_b = (const float*)d_in[19];
  const float* fln_g = (const float*)d_in[20];
  const float* fln_b = (const float*)d_in[21];
  float* out = (float*)d_out;

  unsigned short* ws = (unsigned short*)d_ws;
  const unsigned short* w_inT  = ws + WS_WINT;
  const unsigned short* w_xpT  = ws + WS_WXPT;
  const unsigned short* w_outT = ws + WS_WOUTT;
  const unsigned short* ff1T   = ws + WS_FF1T;
  const unsigned short* ff2T   = ws + WS_FF2T;
  const unsigned short* mixT   = ws + WS_MIXT;

  prep_kernel<<<(WS_TOTAL + 255) / 256, 256, 0, stream>>>(
      mp_in, mp_xproj, mp_out, ff1_w, ff2_w, mix_w, ws);

  for (int s = 0; s < 3; ++s) {
    const float* xp = s == 0 ? x_node : (s == 1 ? x_trace : x_log);
    int SEQ  = (s == 1) ? 256 : 128;
    int slot = (s == 0) ? 0 : (s == 1 ? 128 : 384);
    int grid = 8 * SEQ;
    mamba_front<<<grid, 256, 0, stream>>>(
        xp, SEQ, slot,
        w_inT + (size_t)s * 65536, mp_conv_w + (size_t)s * 1024,
        mp_conv_b + (size_t)s * 256, w_xpT + (size_t)s * 12288,
        mp_dt_w + (size_t)s * 2048, mp_dt_b + (size_t)s * 256,
        mp_Alog + (size_t)s * 4096, mp_D + (size_t)s * 256,
        w_outT + (size_t)s * 32768, out);
  }
  mix_kernel<<<1024, 256, 0, stream>>>(out, mixT, mix_b);
  res_ln<<<4096, 256, 0, stream>>>(out, x_node, x_trace, x_log, an_g, an_b);
  ffn_kernel<<<4096, 256, 0, stream>>>(out, ff1T, ff1_b, ff2T, ff2_b, fln_g, fln_b);
}

// Round 3
// 819.679 us; speedup vs baseline: 5.2820x; 1.4286x over previous
//
#include <hip/hip_runtime.h>

#define DEV __device__ __forceinline__

typedef __attribute__((ext_vector_type(8))) short bf16x8;
typedef __attribute__((ext_vector_type(4))) float f32x4;

DEV f32x4 MF(bf16x8 a, bf16x8 b, f32x4 c) {
  return __builtin_amdgcn_mfma_f32_16x16x32_bf16(a, b, c, 0, 0, 0);
}

DEV float bf2f(unsigned short u) {
  union { unsigned int i; float f; } v; v.i = ((unsigned int)u) << 16; return v.f;
}
DEV unsigned short f2bf(float f) {
  union { float f; unsigned int i; } v; v.f = f;
  unsigned int x = v.i;
  return (unsigned short)((x + 0x7fffu + ((x >> 16) & 1u)) >> 16);
}
#define LOG2E 1.442695041f
#define LN2   0.6931471806f
// fast silu: v * rcp(1 + 2^(-v*log2e)) — v_exp + v_rcp, no fp division
DEV float silu_fast(float v) {
  float e = __builtin_amdgcn_exp2f(v * -LOG2E);
  return v * __builtin_amdgcn_rcpf(1.f + e);
}
// fast softplus: ln(1+e^v) via v_exp/v_log; select v for large v (e overflows)
DEV float softplus_fast(float v) {
  float e = __builtin_amdgcn_exp2f(v * LOG2E);
  float l = __builtin_amdgcn_logf(1.f + e) * LN2;
  return v > 15.f ? v : l;
}

// ws layout (bf16 element offsets)
#define WS_WINT   0        // 3 x [512][128]
#define WS_WXPT   196608   // 3 x [48][256] (cols 40..47 zero)
#define WS_WOUTT  233472   // 3 x [128][256]
#define WS_FF1T   331776   // 3 x [512][128]
#define WS_FF2T   528384   // 3 x [128][512]
#define WS_MIXT   724992   // [256][256]
#define WS_TOTAL  790528

// ---------------------------------------------------------------------------
// prep: transpose+convert all weight matrices into ws as bf16 [N][K]
// ---------------------------------------------------------------------------
__global__ __launch_bounds__(256) void prep_kernel(
    const float* __restrict__ w_in, const float* __restrict__ w_xp,
    const float* __restrict__ w_out, const float* __restrict__ ff1,
    const float* __restrict__ ff2, const float* __restrict__ mixw,
    unsigned short* __restrict__ ws)
{
  int idx = blockIdx.x * 256 + threadIdx.x;
  if (idx >= WS_TOTAL) return;
  float v;
  if (idx < WS_WXPT) {              // w_inT [s][512][128]
    int j = idx, s = j / 65536, r = j % 65536, n = r >> 7, k = r & 127;
    v = w_in[s * 65536 + k * 512 + n];
  } else if (idx < WS_WOUTT) {      // w_xpT [s][48][256]
    int j = idx - WS_WXPT, s = j / 12288, r = j % 12288, n = r >> 8, k = r & 255;
    v = (n < 40) ? w_xp[s * 10240 + k * 40 + n] : 0.f;
  } else if (idx < WS_FF1T) {       // w_outT [s][128][256]
    int j = idx - WS_WOUTT, s = j / 32768, r = j % 32768, n = r >> 8, k = r & 255;
    v = w_out[s * 32768 + k * 128 + n];
  } else if (idx < WS_FF2T) {       // ff1T [s][512][128]
    int j = idx - WS_FF1T, s = j / 65536, r = j % 65536, n = r >> 7, k = r & 127;
    v = ff1[s * 65536 + k * 512 + n];
  } else if (idx < WS_MIXT) {       // ff2T [s][128][512]
    int j = idx - WS_FF2T, s = j / 65536, r = j % 65536, n = r >> 9, k = r & 511;
    v = ff2[s * 65536 + k * 128 + n];
  } else {                          // mixT [256][256]
    int j = idx - WS_MIXT, n = j >> 8, k = j & 255;
    v = mixw[k * 256 + n];
  }
  ws[idx] = f2bf(v);
}

// ---------------------------------------------------------------------------
// Fused mamba front, all 3 streams in one launch. One block = one sequence.
// s==1 (trace) additionally fuses residual + LayerNorm into the epilogue.
// ---------------------------------------------------------------------------
__global__ __launch_bounds__(256, 2) void mamba_front(
    const float* __restrict__ xn, const float* __restrict__ xt,
    const float* __restrict__ xl,
    const unsigned short* __restrict__ w_inT_all,
    const float* __restrict__ conv_w_all, const float* __restrict__ conv_b_all,
    const unsigned short* __restrict__ w_xpT_all,
    const float* __restrict__ dt_w_all, const float* __restrict__ dt_b_all,
    const float* __restrict__ Alog_all, const float* __restrict__ Dp_all,
    const unsigned short* __restrict__ w_outT_all,
    const float* __restrict__ an_g, const float* __restrict__ an_b,
    float* __restrict__ out)
{
  __shared__ __attribute__((aligned(16))) unsigned short xcz[64 * 512]; // [t][n^swz]
  __shared__ __attribute__((aligned(16))) char aux[16384];
  unsigned short* xs = (unsigned short*)aux;   // [64][128] bf16 swizzled
  float* dbc = (float*)aux;                    // [64][48] f32 (after GEMM1+conv)

  const int tid = threadIdx.x;
  const int lane = tid & 63;
  const int wv = tid >> 6;
  const int lr = lane & 15;
  const int kg = lane >> 4;

  int blk = blockIdx.x, s, q;
  if (blk < 1024)      { s = 0; q = blk; }
  else if (blk < 3072) { s = 1; q = blk - 1024; }
  else                 { s = 2; q = blk - 3072; }
  const int SEQ = (s == 1) ? 256 : 128;
  const int slot_base = (s == 0) ? 0 : (s == 1 ? 128 : 384);
  const float* x = (s == 0) ? xn : (s == 1 ? xt : xl);
  const unsigned short* w_inT  = w_inT_all  + (size_t)s * 65536;
  const unsigned short* w_xpT  = w_xpT_all  + (size_t)s * 12288;
  const unsigned short* w_outT = w_outT_all + (size_t)s * 32768;
  const float* conv_w = conv_w_all + s * 1024;
  const float* conv_b = conv_b_all + s * 256;
  const float* dt_w   = dt_w_all + s * 2048;
  const float* dt_b   = dt_b_all + s * 256;
  const float* Alog   = Alog_all + s * 4096;
  const float* Dp     = Dp_all + s * 256;

  const int b = q / SEQ, n = q - b * SEQ;
  const float* xb = x + ((size_t)b * 64 * SEQ + n) * 128;

  // stage x -> xs (bf16, XOR-swizzled)
  for (int idx = tid; idx < 2048; idx += 256) {
    int t = idx >> 5, qd = (idx & 31) << 2;
    float4 v = *(const float4*)(xb + (size_t)t * SEQ * 128 + qd);
    uint2 p;
    p.x = f2bf(v.x) | ((unsigned int)f2bf(v.y) << 16);
    p.y = f2bf(v.z) | ((unsigned int)f2bf(v.w) << 16);
    *(uint2*)(&xs[t * 128 + (qd ^ ((t & 7) << 3))]) = p;
  }
  __syncthreads();

  // GEMM1 (swapped): xz^T[n][t] = w_inT[n][:] . x[t][:]
  {
    bf16x8 bx[4][4];
#pragma unroll
    for (int jt = 0; jt < 4; ++jt)
#pragma unroll
      for (int ks = 0; ks < 4; ++ks) {
        int t = jt * 16 + lr;
        bx[jt][ks] = *(const bf16x8*)(&xs[t * 128 + ((ks * 32 + kg * 8) ^ ((t & 7) << 3))]);
      }
    const int nb = wv * 128;
#pragma unroll
    for (int at = 0; at < 8; ++at) {
      bf16x8 av[4];
      int arow = nb + at * 16 + lr;
#pragma unroll
      for (int ks = 0; ks < 4; ++ks)
        av[ks] = *(const bf16x8*)(w_inT + arow * 128 + ks * 32 + kg * 8);
#pragma unroll
      for (int jt = 0; jt < 4; ++jt) {
        f32x4 c = {0.f, 0.f, 0.f, 0.f};
#pragma unroll
        for (int ks = 0; ks < 4; ++ks) c = MF(av[ks], bx[jt][ks], c);
        int t = jt * 16 + lr;
        int n0 = nb + at * 16 + kg * 4;
        uint2 p;
        p.x = f2bf(c[0]) | ((unsigned int)f2bf(c[1]) << 16);
        p.y = f2bf(c[2]) | ((unsigned int)f2bf(c[3]) << 16);
        *(uint2*)(&xcz[t * 512 + (n0 ^ ((t & 7) << 3))]) = p;
      }
    }
  }
  __syncthreads();

  // causal depthwise conv + bias + silu, chunked x16 so LDS reads batch
  {
    const int d = tid;
    float cw0 = conv_w[d * 4 + 0], cw1 = conv_w[d * 4 + 1];
    float cw2 = conv_w[d * 4 + 2], cw3 = conv_w[d * 4 + 3];
    float cb = conv_b[d];
    float xm3 = 0.f, xm2 = 0.f, xm1 = 0.f;
    for (int c0 = 0; c0 < 64; c0 += 16) {
      float xv[16];
#pragma unroll
      for (int u = 0; u < 16; ++u) {
        int t = c0 + u;
        xv[u] = bf2f(xcz[t * 512 + (d ^ ((t & 7) << 3))]);
      }
#pragma unroll
      for (int u = 0; u < 16; ++u) {
        float sv = fmaf(cw0, xm3, fmaf(cw1, xm2, fmaf(cw2, xm1, fmaf(cw3, xv[u], cb))));
        xm3 = xm2; xm2 = xm1; xm1 = xv[u];
        xv[u] = silu_fast(sv);
      }
#pragma unroll
      for (int u = 0; u < 16; ++u) {
        int t = c0 + u;
        xcz[t * 512 + (d ^ ((t & 7) << 3))] = f2bf(xv[u]);
      }
    }
  }
  __syncthreads();

  // x_proj via MFMA: dbc[t][c] = xc[t][:] . w_xpT[c][:]   (wave = t-tile)
  {
    bf16x8 av[8];
    int ta = wv * 16 + lr;
#pragma unroll
    for (int ks = 0; ks < 8; ++ks)
      av[ks] = *(const bf16x8*)(&xcz[ta * 512 + ((ks * 32 + kg * 8) ^ ((ta & 7) << 3))]);
#pragma unroll
    for (int ct = 0; ct < 3; ++ct) {
      f32x4 c = {0.f, 0.f, 0.f, 0.f};
#pragma unroll
      for (int ks = 0; ks < 8; ++ks) {
        bf16x8 bv = *(const bf16x8*)(w_xpT + (ct * 16 + lr) * 256 + ks * 32 + kg * 8);
        c = MF(av[ks], bv, c);
      }
      int tt = wv * 16 + kg * 4;
#pragma unroll
      for (int r = 0; r < 4; ++r)
        dbc[(tt + r) * 48 + ct * 16 + lr] = c[r];
    }
  }
  __syncthreads();

  // selective scan + gate (thread = d)
  {
    const int d = tid;
    float dtw[8];
#pragma unroll
    for (int r = 0; r < 8; ++r) dtw[r] = dt_w[r * 256 + d];
    const float dtb = dt_b[d];
    // Af2[s] = A[s]*log2e (A = -exp(Alog)); detect geometric structure
    float Af2[16];
#pragma unroll
    for (int s2 = 0; s2 < 16; ++s2)
      Af2[s2] = -__builtin_amdgcn_exp2f(Alog[d * 16 + s2] * LOG2E) * LOG2E;
    const float af0l2 = Af2[0];
    bool geo = true;
#pragma unroll
    for (int s2 = 1; s2 < 16; ++s2)
      geo = geo && (fabsf(Af2[s2] - (float)(s2 + 1) * af0l2) <= 1e-4f * fabsf(Af2[s2]));
    const float Dv = Dp[d];
    float h[16];
#pragma unroll
    for (int s2 = 0; s2 < 16; ++s2) h[s2] = 0.f;

    const int eoff = d;           // col for xc
    const int zoff = 256 + d;     // col for z
    if (geo) {
      // dA[s] = r1^(s+1): ONE v_exp per step instead of 16
#pragma unroll 2
      for (int t = 0; t < 64; ++t) {
        const float* dr = &dbc[t * 48];
        float dtv = dtb;
#pragma unroll
        for (int r = 0; r < 8; ++r) dtv = fmaf(dtw[r], dr[r], dtv);
        dtv = softplus_fast(dtv);
        int sw = (t & 7) << 3;
        int e = t * 512 + (eoff ^ sw);
        float xv = bf2f(xcz[e]);
        float zf = bf2f(xcz[t * 512 + (zoff ^ sw)]);
        float cf = dtv * xv;
        float r1 = __builtin_amdgcn_exp2f(dtv * af0l2);
        float p = 1.f, y = 0.f;
#pragma unroll
        for (int s2 = 0; s2 < 16; ++s2) {
          p *= r1;
          h[s2] = fmaf(p, h[s2], cf * dr[8 + s2]);
          y = fmaf(h[s2], dr[24 + s2], y);
        }
        xcz[e] = f2bf((y + xv * Dv) * silu_fast(zf));
      }
    } else {
#pragma unroll 2
      for (int t = 0; t < 64; ++t) {
        const float* dr = &dbc[t * 48];
        float dtv = dtb;
#pragma unroll
        for (int r = 0; r < 8; ++r) dtv = fmaf(dtw[r], dr[r], dtv);
        dtv = softplus_fast(dtv);
        int sw = (t & 7) << 3;
        int e = t * 512 + (eoff ^ sw);
        float xv = bf2f(xcz[e]);
        float zf = bf2f(xcz[t * 512 + (zoff ^ sw)]);
        float cf = dtv * xv;
        float y = 0.f;
#pragma unroll
        for (int s2 = 0; s2 < 16; ++s2) {
          float dA = __builtin_amdgcn_exp2f(dtv * Af2[s2]);
          h[s2] = fmaf(dA, h[s2], cf * dr[8 + s2]);
          y = fmaf(h[s2], dr[24 + s2], y);
        }
        xcz[e] = f2bf((y + xv * Dv) * silu_fast(zf));
      }
    }
  }
  __syncthreads();

  // GEMM-out via MFMA: y[t][:] . w_outT[c][:]  (wave = t-tile)
  {
    bf16x8 av[8];
    int ta = wv * 16 + lr;
#pragma unroll
    for (int ks = 0; ks < 8; ++ks)
      av[ks] = *(const bf16x8*)(&xcz[ta * 512 + ((ks * 32 + kg * 8) ^ ((ta & 7) << 3))]);
    f32x4 acc[8];
#pragma unroll
    for (int ct = 0; ct < 8; ++ct) {
      f32x4 c = {0.f, 0.f, 0.f, 0.f};
#pragma unroll
      for (int ks = 0; ks < 8; ++ks) {
        bf16x8 bv = *(const bf16x8*)(w_outT + (ct * 16 + lr) * 256 + ks * 32 + kg * 8);
        c = MF(av[ks], bv, c);
      }
      acc[ct] = c;
    }
    size_t ob = (size_t)b * 64 * 512 * 128 + (size_t)(slot_base + n) * 128;
    const int trow = wv * 16 + kg * 4;
    if (s != 1) {
      // node/log: raw y (mix kernel does residual+LN later)
#pragma unroll
      for (int ct = 0; ct < 8; ++ct) {
        int cc = ct * 16 + lr;
#pragma unroll
        for (int r = 0; r < 4; ++r)
          out[ob + (size_t)(trow + r) * 65536 + cc] = acc[ct][r];
      }
    } else {
      // trace: fused residual (x_trace, f32 from global) + LayerNorm(an[1])
      float sum[4] = {0.f, 0.f, 0.f, 0.f}, sq[4] = {0.f, 0.f, 0.f, 0.f};
#pragma unroll
      for (int ct = 0; ct < 8; ++ct) {
        int col = ct * 16 + lr;
#pragma unroll
        for (int r = 0; r < 4; ++r) {
          int t = trow + r;
          float xr = xb[(size_t)t * SEQ * 128 + col];
          float v = acc[ct][r] + xr;
          acc[ct][r] = v;
          sum[r] += v; sq[r] += v * v;
        }
      }
      float mn[4], rstd[4];
#pragma unroll
      for (int r = 0; r < 4; ++r) {
        float s1 = sum[r], s2 = sq[r];
        s1 += __shfl_xor(s1, 1); s2 += __shfl_xor(s2, 1);
        s1 += __shfl_xor(s1, 2); s2 += __shfl_xor(s2, 2);
        s1 += __shfl_xor(s1, 4); s2 += __shfl_xor(s2, 4);
        s1 += __shfl_xor(s1, 8); s2 += __shfl_xor(s2, 8);
        float mean = s1 * (1.f / 128.f);
        float var = s2 * (1.f / 128.f) - mean * mean;
        mn[r] = mean;
        rstd[r] = rsqrtf(var + 1e-5f);
      }
      const float* G  = an_g + 128;
      const float* Bv = an_b + 128;
#pragma unroll
      for (int ct = 0; ct < 8; ++ct) {
        int col = ct * 16 + lr;
        float gc = G[col], bc = Bv[col];
#pragma unroll
        for (int r = 0; r < 4; ++r)
          out[ob + (size_t)(trow + r) * 65536 + col] = (acc[ct][r] - mn[r]) * rstd[r] * gc + bc;
      }
    }
  }
}

// ---------------------------------------------------------------------------
// mix + residual + LayerNorm fused: cat=[yn||yl]; v = cat + silu(cat@W+b) + x;
// out = LN(v). One block = one (b,n), 64 w-tokens.
// ---------------------------------------------------------------------------
__global__ __launch_bounds__(256, 4) void mix_kernel(
    float* __restrict__ out, const unsigned short* __restrict__ mixT,
    const float* __restrict__ mix_b,
    const float* __restrict__ xn, const float* __restrict__ xl,
    const float* __restrict__ an_g, const float* __restrict__ an_b)
{
  __shared__ __attribute__((aligned(16))) unsigned short cs[64 * 256];

  const int tid = threadIdx.x;
  const int lane = tid & 63;
  const int wv = tid >> 6;
  const int lr = lane & 15;
  const int kg = lane >> 4;
  const int bn = blockIdx.x;
  const int b = bn >> 7, n = bn & 127;
  const size_t base_n = (((size_t)b * 64) * 512 + n) * 128;
  const size_t base_l = (((size_t)b * 64) * 512 + 384 + n) * 128;

  for (int idx = tid; idx < 4096; idx += 256) {
    int t = idx >> 6, r = idx & 63;
    int half = r >> 5, qd = (r & 31) << 2;
    const float* src = out + (half ? base_l : base_n) + (size_t)t * 65536 + qd;
    float4 v = *(const float4*)src;
    int col = half * 128 + qd;
    uint2 p;
    p.x = f2bf(v.x) | ((unsigned int)f2bf(v.y) << 16);
    p.y = f2bf(v.z) | ((unsigned int)f2bf(v.w) << 16);
    *(uint2*)(&cs[t * 256 + (col ^ ((t & 7) << 3))]) = p;
  }
  __syncthreads();

  bf16x8 av[8];
  int ta = wv * 16 + lr;
#pragma unroll
  for (int ks = 0; ks < 8; ++ks)
    av[ks] = *(const bf16x8*)(&cs[ta * 256 + ((ks * 32 + kg * 8) ^ ((ta & 7) << 3))]);

  const int trow = wv * 16 + kg * 4;
#pragma unroll
  for (int half = 0; half < 2; ++half) {
    const float* xres_base = half ? xl : xn;
    f32x4 acc[8];
#pragma unroll
    for (int ct = 0; ct < 8; ++ct) {
      f32x4 c = {0.f, 0.f, 0.f, 0.f};
      int colg = half * 128 + ct * 16 + lr;
#pragma unroll
      for (int ks = 0; ks < 8; ++ks) {
        bf16x8 bv = *(const bf16x8*)(mixT + colg * 256 + ks * 32 + kg * 8);
        c = MF(av[ks], bv, c);
      }
      acc[ct] = c;
    }
    float sum[4] = {0.f, 0.f, 0.f, 0.f}, sq[4] = {0.f, 0.f, 0.f, 0.f};
#pragma unroll
    for (int ct = 0; ct < 8; ++ct) {
      int col = ct * 16 + lr;
      int colg = half * 128 + col;
      float bcol = mix_b[colg];
#pragma unroll
      for (int r = 0; r < 4; ++r) {
        int t = trow + r;
        float orig = bf2f(cs[t * 256 + (colg ^ ((t & 7) << 3))]);
        float xr = xres_base[(((size_t)b * 64 + t) * 128 + n) * 128 + col];
        float v = orig + silu_fast(acc[ct][r] + bcol) + xr;
        acc[ct][r] = v;
        sum[r] += v; sq[r] += v * v;
      }
    }
    float mn[4], rstd[4];
#pragma unroll
    for (int r = 0; r < 4; ++r) {
      float s1 = sum[r], s2 = sq[r];
      s1 += __shfl_xor(s1, 1); s2 += __shfl_xor(s2, 1);
      s1 += __shfl_xor(s1, 2); s2 += __shfl_xor(s2, 2);
      s1 += __shfl_xor(s1, 4); s2 += __shfl_xor(s2, 4);
      s1 += __shfl_xor(s1, 8); s2 += __shfl_xor(s2, 8);
      float mean = s1 * (1.f / 128.f);
      float var = s2 * (1.f / 128.f) - mean * mean;
      mn[r] = mean;
      rstd[r] = rsqrtf(var + 1e-5f);
    }
    const float* G  = an_g + (half ? 256 : 0);
    const float* Bv = an_b + (half ? 256 : 0);
    size_t base = half ? base_l : base_n;
#pragma unroll
    for (int ct = 0; ct < 8; ++ct) {
      int col = ct * 16 + lr;
      float gc = G[col], bc = Bv[col];
#pragma unroll
      for (int r = 0; r < 4; ++r)
        out[base + (size_t)(trow + r) * 65536 + col] = (acc[ct][r] - mn[r]) * rstd[r] * gc + bc;
    }
  }
}

// ---------------------------------------------------------------------------
// FFN via MFMA: h = leaky_relu(x@ff1+b1); out = LN(h@ff2 + b2 + x). In place.
// ---------------------------------------------------------------------------
__global__ __launch_bounds__(256, 2) void ffn_kernel(
    float* __restrict__ out,
    const unsigned short* __restrict__ ff1T, const float* __restrict__ b1,
    const unsigned short* __restrict__ ff2T, const float* __restrict__ b2,
    const float* __restrict__ g, const float* __restrict__ bb)
{
  __shared__ __attribute__((aligned(16))) unsigned short hT[64 * 512];
  __shared__ __attribute__((aligned(16))) unsigned short xs[64 * 128];

  const int tid = threadIdx.x;
  const int lane = tid & 63;
  const int wv = tid >> 6;
  const int lr = lane & 15;
  const int kg = lane >> 4;
  const int tok0 = blockIdx.x * 64;
  const int slot0 = tok0 & 511;
  const int s = slot0 < 128 ? 0 : (slot0 < 384 ? 1 : 2);
  const unsigned short* F1 = ff1T + (size_t)s * 65536;
  const unsigned short* F2 = ff2T + (size_t)s * 65536;
  const float* B1 = b1 + s * 512;
  const float* B2 = b2 + s * 128;
  const float* G = g + s * 128;
  const float* Bb = bb + s * 128;

  for (int idx = tid; idx < 2048; idx += 256) {
    int t = idx >> 5, qd = (idx & 31) << 2;
    float4 v = *(const float4*)(out + (size_t)(tok0 + t) * 128 + qd);
    uint2 p;
    p.x = f2bf(v.x) | ((unsigned int)f2bf(v.y) << 16);
    p.y = f2bf(v.z) | ((unsigned int)f2bf(v.w) << 16);
    *(uint2*)(&xs[t * 128 + (qd ^ ((t & 7) << 3))]) = p;
  }
  __syncthreads();

  // GEMM1 (swapped): h^T[n][t] = ff1T[n][:] . x[t][:], +b1, leaky-relu
  {
    bf16x8 bx[4][4];
#pragma unroll
    for (int jt = 0; jt < 4; ++jt)
#pragma unroll
      for (int ks = 0; ks < 4; ++ks) {
        int t = jt * 16 + lr;
        bx[jt][ks] = *(const bf16x8*)(&xs[t * 128 + ((ks * 32 + kg * 8) ^ ((t & 7) << 3))]);
      }
    const int nb = wv * 128;
#pragma unroll
    for (int at = 0; at < 8; ++at) {
      bf16x8 av[4];
      int arow = nb + at * 16 + lr;
#pragma unroll
      for (int ks = 0; ks < 4; ++ks)
        av[ks] = *(const bf16x8*)(F1 + arow * 128 + ks * 32 + kg * 8);
      float4 bias = *(const float4*)(B1 + nb + at * 16 + kg * 4);
#pragma unroll
      for (int jt = 0; jt < 4; ++jt) {
        f32x4 c = {0.f, 0.f, 0.f, 0.f};
#pragma unroll
        for (int ks = 0; ks < 4; ++ks) c = MF(av[ks], bx[jt][ks], c);
        float v0 = c[0] + bias.x; v0 = v0 > 0.f ? v0 : 0.01f * v0;
        float v1 = c[1] + bias.y; v1 = v1 > 0.f ? v1 : 0.01f * v1;
        float v2 = c[2] + bias.z; v2 = v2 > 0.f ? v2 : 0.01f * v2;
        float v3 = c[3] + bias.w; v3 = v3 > 0.f ? v3 : 0.01f * v3;
        int t = jt * 16 + lr;
        int n0 = nb + at * 16 + kg * 4;
        uint2 p;
        p.x = f2bf(v0) | ((unsigned int)f2bf(v1) << 16);
        p.y = f2bf(v2) | ((unsigned int)f2bf(v3) << 16);
        *(uint2*)(&hT[t * 512 + (n0 ^ ((t & 7) << 3))]) = p;
      }
    }
  }
  __syncthreads();

  // GEMM2: out[t][c] = h[t][:] . ff2T[c][:]   (wave = t-tile), + LN epilogue
  {
    bf16x8 av[16];
    int ta = wv * 16 + lr;
#pragma unroll
    for (int ks = 0; ks < 16; ++ks)
      av[ks] = *(const bf16x8*)(&hT[ta * 512 + ((ks * 32 + kg * 8) ^ ((ta & 7) << 3))]);
    f32x4 acc[8];
#pragma unroll
    for (int ct = 0; ct < 8; ++ct) {
      f32x4 c = {0.f, 0.f, 0.f, 0.f};
#pragma unroll
      for (int ks = 0; ks < 16; ++ks) {
        bf16x8 bv = *(const bf16x8*)(F2 + (ct * 16 + lr) * 512 + ks * 32 + kg * 8);
        c = MF(av[ks], bv, c);
      }
      acc[ct] = c;
    }

    float v[8][4];
    float sum[4] = {0.f, 0.f, 0.f, 0.f}, sq[4] = {0.f, 0.f, 0.f, 0.f};
    const int trow = wv * 16 + kg * 4;
#pragma unroll
    for (int ct = 0; ct < 8; ++ct) {
      int col = ct * 16 + lr;
      float b2c = B2[col];
#pragma unroll
      for (int r = 0; r < 4; ++r) {
        int t = trow + r;
        float xr = bf2f(xs[t * 128 + (col ^ ((t & 7) << 3))]);
        float val = acc[ct][r] + b2c + xr;
        v[ct][r] = val;
        sum[r] += val; sq[r] += val * val;
      }
    }
    float mn[4], rstd[4];
#pragma unroll
    for (int r = 0; r < 4; ++r) {
      float s1 = sum[r], s2 = sq[r];
      s1 += __shfl_xor(s1, 1); s2 += __shfl_xor(s2, 1);
      s1 += __shfl_xor(s1, 2); s2 += __shfl_xor(s2, 2);
      s1 += __shfl_xor(s1, 4); s2 += __shfl_xor(s2, 4);
      s1 += __shfl_xor(s1, 8); s2 += __shfl_xor(s2, 8);
      float mean = s1 * (1.f / 128.f);
      float var = s2 * (1.f / 128.f) - mean * mean;
      mn[r] = mean;
      rstd[r] = rsqrtf(var + 1e-5f);
    }
#pragma unroll
    for (int ct = 0; ct < 8; ++ct) {
      int col = ct * 16 + lr;
      float gc = G[col], bc = Bb[col];
#pragma unroll
      for (int r = 0; r < 4; ++r)
        out[(size_t)(tok0 + trow + r) * 128 + col] = (v[ct][r] - mn[r]) * rstd[r] * gc + bc;
    }
  }
}

extern "C" void kernel_launch(void* const* d_in, const int* in_sizes, int n_in,
                              void* d_out, int out_size, void* d_ws, size_t ws_size,
                              hipStream_t stream) {
  (void)in_sizes; (void)n_in; (void)out_size; (void)ws_size;
  const float* x_node  = (const float*)d_in[0];
  const float* x_trace = (const float*)d_in[1];
  const float* x_log   = (const float*)d_in[2];
  const float* mp_in     = (const float*)d_in[3];
  const float* mp_conv_w = (const float*)d_in[4];
  const float* mp_conv_b = (const float*)d_in[5];
  const float* mp_xproj  = (const float*)d_in[6];
  const float* mp_dt_w   = (const float*)d_in[7];
  const float* mp_dt_b   = (const float*)d_in[8];
  const float* mp_Alog   = (const float*)d_in[9];
  const float* mp_D      = (const float*)d_in[10];
  const float* mp_out    = (const float*)d_in[11];
  const float* mix_w = (const float*)d_in[12];
  const float* mix_b = (const float*)d_in[13];
  const float* an_g  = (const float*)d_in[14];
  const float* an_b  = (const float*)d_in[15];
  const float* ff1_w = (const float*)d_in[16];
  const float* ff1_b = (const float*)d_in[17];
  const float* ff2_w = (const float*)d_in[18];
  const float* ff2_b = (const float*)d_in[19];
  const float* fln_g = (const float*)d_in[20];
  const float* fln_b = (const float*)d_in[21];
  float* out = (float*)d_out;

  unsigned short* ws = (unsigned short*)d_ws;

  prep_kernel<<<(WS_TOTAL + 255) / 256, 256, 0, stream>>>(
      mp_in, mp_xproj, mp_out, ff1_w, ff2_w, mix_w, ws);

  mamba_front<<<4096, 256, 0, stream>>>(
      x_node, x_trace, x_log,
      ws + WS_WINT, mp_conv_w, mp_conv_b, ws + WS_WXPT,
      mp_dt_w, mp_dt_b, mp_Alog, mp_D, ws + WS_WOUTT,
      an_g, an_b, out);

  mix_kernel<<<1024, 256, 0, stream>>>(out, ws + WS_MIXT, mix_b,
                                       x_node, x_log, an_g, an_b);

  ffn_kernel<<<4096, 256, 0, stream>>>(out, ws + WS_FF1T, ff1_b,
                                       ws + WS_FF2T, ff2_b, fln_g, fln_b);
}